// Round 1
// baseline (239.106 us; speedup 1.0000x reference)
//
#include <hip/hip_runtime.h>

#define M1   33      // LPC_ORDER + 1
#define BLK  256     // rows per block (threads per block)
// floats per block staged in LDS
#define BLK_ELEMS (BLK * M1)          // 8448 floats
#define BLK_VEC4  (BLK_ELEMS / 4)     // 2112 float4
#define VEC_FULL  (BLK_VEC4 / BLK)    // 8 full iterations
#define VEC_REM   (BLK_VEC4 - VEC_FULL * BLK)  // 64 remaining float4

__global__ __launch_bounds__(BLK)
void parcor_to_lpc_kernel(const float* __restrict__ k, float* __restrict__ out) {
    __shared__ float lds[BLK_ELEMS];

    const size_t base = (size_t)blockIdx.x * BLK_ELEMS;
    const float4* __restrict__ gsrc4 = (const float4*)(k + base);
    float4* __restrict__ gdst4 = (float4*)(out + base);
    float4* lds4 = (float4*)lds;

    // ---- coalesced global -> LDS staging (16B/lane) ----
    #pragma unroll
    for (int i = 0; i < VEC_FULL; ++i)
        lds4[i * BLK + threadIdx.x] = gsrc4[i * BLK + threadIdx.x];
    if (threadIdx.x < VEC_REM)
        lds4[VEC_FULL * BLK + threadIdx.x] = gsrc4[VEC_FULL * BLK + threadIdx.x];
    __syncthreads();

    // ---- LDS -> registers: row stride 33 floats => bank (tid + j) % 32,
    //      2-way aliasing across the wave64 = conflict-free on gfx950 ----
    const int t = threadIdx.x;
    float a[M1];
    #pragma unroll
    for (int j = 0; j < M1; ++j)
        a[j] = lds[t * M1 + j];

    // ---- Levinson step-up recursion, fully unrolled, in registers.
    //      new a[j] = a[j] + km * a[m-j] for j in 1..m-1 (old values).
    //      a[m] is untouched by iterations < m, so km = a[m]. ----
    #pragma unroll
    for (int m = 2; m < M1; ++m) {
        const float km = a[m];
        #pragma unroll
        for (int j = 1; 2 * j < m; ++j) {
            const float x = a[j];
            const float y = a[m - j];
            a[j]     = fmaf(km, y, x);
            a[m - j] = fmaf(km, x, y);
        }
        if ((m & 1) == 0) {
            const int j = m >> 1;
            a[j] = fmaf(km, a[j], a[j]);   // a[j] * (1 + km)
        }
    }

    // ---- registers -> LDS -> coalesced global store ----
    __syncthreads();   // staging buffer reuse
    #pragma unroll
    for (int j = 0; j < M1; ++j)
        lds[t * M1 + j] = a[j];
    __syncthreads();

    #pragma unroll
    for (int i = 0; i < VEC_FULL; ++i)
        gdst4[i * BLK + threadIdx.x] = lds4[i * BLK + threadIdx.x];
    if (threadIdx.x < VEC_REM)
        gdst4[VEC_FULL * BLK + threadIdx.x] = lds4[VEC_FULL * BLK + threadIdx.x];
}

// Fallback for a row-count not divisible by BLK (not hit for the 16x65536 shape):
// one thread per row, scalar loads.
__global__ void parcor_to_lpc_tail_kernel(const float* __restrict__ k,
                                          float* __restrict__ out,
                                          int row_start, int nrows) {
    const int row = row_start + blockIdx.x * blockDim.x + threadIdx.x;
    if (row >= nrows) return;
    const float* src = k + (size_t)row * M1;
    float* dst = out + (size_t)row * M1;
    float a[M1];
    #pragma unroll
    for (int j = 0; j < M1; ++j) a[j] = src[j];
    #pragma unroll
    for (int m = 2; m < M1; ++m) {
        const float km = a[m];
        #pragma unroll
        for (int j = 1; 2 * j < m; ++j) {
            const float x = a[j];
            const float y = a[m - j];
            a[j]     = fmaf(km, y, x);
            a[m - j] = fmaf(km, x, y);
        }
        if ((m & 1) == 0) {
            const int j = m >> 1;
            a[j] = fmaf(km, a[j], a[j]);
        }
    }
    #pragma unroll
    for (int j = 0; j < M1; ++j) dst[j] = a[j];
}

extern "C" void kernel_launch(void* const* d_in, const int* in_sizes, int n_in,
                              void* d_out, int out_size, void* d_ws, size_t ws_size,
                              hipStream_t stream) {
    const float* k = (const float*)d_in[0];
    float* out = (float*)d_out;

    const int nrows = in_sizes[0] / M1;      // 16 * 65536 = 1,048,576
    const int nblk  = nrows / BLK;           // 4096 full blocks
    const int rem   = nrows - nblk * BLK;

    if (nblk > 0)
        parcor_to_lpc_kernel<<<nblk, BLK, 0, stream>>>(k, out);
    if (rem > 0)
        parcor_to_lpc_tail_kernel<<<(rem + BLK - 1) / BLK, BLK, 0, stream>>>(
            k, out, nblk * BLK, nrows);
}

// Round 2
// 237.801 us; speedup vs baseline: 1.0055x; 1.0055x over previous
//
#include <hip/hip_runtime.h>

#define M1   33      // LPC_ORDER + 1
#define BLK  128     // rows per block (threads per block); LDS = 16.9 KB -> 9 blocks/CU
// floats per block staged in LDS
#define BLK_ELEMS (BLK * M1)          // 4224 floats
#define BLK_VEC4  (BLK_ELEMS / 4)     // 1056 float4
#define VEC_FULL  (BLK_VEC4 / BLK)    // 8 full iterations
#define VEC_REM   (BLK_VEC4 - VEC_FULL * BLK)  // 32 remaining float4

__global__ __launch_bounds__(BLK)
void parcor_to_lpc_kernel(const float* __restrict__ k, float* __restrict__ out) {
    __shared__ float lds[BLK_ELEMS];

    const size_t base = (size_t)blockIdx.x * BLK_ELEMS;
    const float4* __restrict__ gsrc4 = (const float4*)(k + base);
    float4* __restrict__ gdst4 = (float4*)(out + base);
    float4* lds4 = (float4*)lds;

    // ---- coalesced global -> LDS staging (16B/lane) ----
    #pragma unroll
    for (int i = 0; i < VEC_FULL; ++i)
        lds4[i * BLK + threadIdx.x] = gsrc4[i * BLK + threadIdx.x];
    if (threadIdx.x < VEC_REM)
        lds4[VEC_FULL * BLK + threadIdx.x] = gsrc4[VEC_FULL * BLK + threadIdx.x];
    __syncthreads();   // staging writes cross rows -> barrier before row reads

    // ---- LDS -> registers: row stride 33 floats => bank (t + j) % 32,
    //      2-way aliasing across the wave64 = conflict-free on gfx950 ----
    const int t = threadIdx.x;
    float a[M1];
    #pragma unroll
    for (int j = 0; j < M1; ++j)
        a[j] = lds[t * M1 + j];

    // ---- Levinson step-up recursion, fully unrolled, in registers ----
    #pragma unroll
    for (int m = 2; m < M1; ++m) {
        const float km = a[m];
        #pragma unroll
        for (int j = 1; 2 * j < m; ++j) {
            const float x = a[j];
            const float y = a[m - j];
            a[j]     = fmaf(km, y, x);
            a[m - j] = fmaf(km, x, y);
        }
        if ((m & 1) == 0) {
            const int j = m >> 1;
            a[j] = fmaf(km, a[j], a[j]);   // a[j] * (1 + km)
        }
    }

    // ---- registers -> LDS (own row only: no barrier needed vs own-row reads) ----
    #pragma unroll
    for (int j = 0; j < M1; ++j)
        lds[t * M1 + j] = a[j];
    __syncthreads();   // final store reads across rows

    #pragma unroll
    for (int i = 0; i < VEC_FULL; ++i)
        gdst4[i * BLK + threadIdx.x] = lds4[i * BLK + threadIdx.x];
    if (threadIdx.x < VEC_REM)
        gdst4[VEC_FULL * BLK + threadIdx.x] = lds4[VEC_FULL * BLK + threadIdx.x];
}

// Fallback for a row-count not divisible by BLK (not hit for the 16x65536 shape).
__global__ void parcor_to_lpc_tail_kernel(const float* __restrict__ k,
                                          float* __restrict__ out,
                                          int row_start, int nrows) {
    const int row = row_start + blockIdx.x * blockDim.x + threadIdx.x;
    if (row >= nrows) return;
    const float* src = k + (size_t)row * M1;
    float* dst = out + (size_t)row * M1;
    float a[M1];
    #pragma unroll
    for (int j = 0; j < M1; ++j) a[j] = src[j];
    #pragma unroll
    for (int m = 2; m < M1; ++m) {
        const float km = a[m];
        #pragma unroll
        for (int j = 1; 2 * j < m; ++j) {
            const float x = a[j];
            const float y = a[m - j];
            a[j]     = fmaf(km, y, x);
            a[m - j] = fmaf(km, x, y);
        }
        if ((m & 1) == 0) {
            const int j = m >> 1;
            a[j] = fmaf(km, a[j], a[j]);
        }
    }
    #pragma unroll
    for (int j = 0; j < M1; ++j) dst[j] = a[j];
}

extern "C" void kernel_launch(void* const* d_in, const int* in_sizes, int n_in,
                              void* d_out, int out_size, void* d_ws, size_t ws_size,
                              hipStream_t stream) {
    const float* k = (const float*)d_in[0];
    float* out = (float*)d_out;

    const int nrows = in_sizes[0] / M1;      // 16 * 65536 = 1,048,576
    const int nblk  = nrows / BLK;           // 8192 full blocks
    const int rem   = nrows - nblk * BLK;

    if (nblk > 0)
        parcor_to_lpc_kernel<<<nblk, BLK, 0, stream>>>(k, out);
    if (rem > 0)
        parcor_to_lpc_tail_kernel<<<(rem + BLK - 1) / BLK, BLK, 0, stream>>>(
            k, out, nblk * BLK, nrows);
}